// Round 7
// baseline (50.748 us; speedup 1.0000x reference)
//
#include <hip/hip_runtime.h>
#include <math.h>

typedef __attribute__((ext_vector_type(4))) float f32x4;
typedef __attribute__((ext_vector_type(8))) short s16x8;

__device__ __forceinline__ short f2bf_rne(float f) {
  unsigned u = __float_as_uint(f);
  unsigned r = u + 0x7FFFu + ((u >> 16) & 1u);
  return (short)(r >> 16);
}
__device__ __forceinline__ float bf2f(short b) {
  return __uint_as_float(((unsigned)(unsigned short)b) << 16);
}

// ---------------- W1 -> bf16 hi/lo fragment pre-pack ----------------
// Fragment convention (must match main kernel's A build):
//   frag element j of lane l holds k = kchunk*32 + (l>>4)*8 + j, col = nt*16 + (l&15)
// ws layout: slot = (c*4 + nt)*2 + sel (sel 0=hi,1=lo); frag addr = (slot*64 + l)*8 ushorts
__global__ __launch_bounds__(256) void prep_w1(const float* __restrict__ W1,
                                               unsigned short* __restrict__ wf) {
  const int c   = blockIdx.x;         // k-chunk 0..39
  const int l   = threadIdx.x & 63;
  const int nt  = threadIdx.x >> 6;   // 0..3
  const int kb  = c * 32 + (l >> 4) * 8;
  const int col = nt * 16 + (l & 15);
  s16x8 hi, lo;
#pragma unroll
  for (int j = 0; j < 8; ++j) {
    float f = W1[(kb + j) * 64 + col];
    short h = f2bf_rne(f);
    hi[j] = h;
    lo[j] = f2bf_rne(f - bf2f(h));
  }
  const int slot = (c * 4 + nt) * 2;
  *(s16x8*)(wf + (size_t)(slot * 64 + l) * 8)       = hi;
  *(s16x8*)(wf + (size_t)((slot + 1) * 64 + l) * 8) = lo;
}

// ---------------- circuit macros (verified rounds 1-2) ----------------
#define APPLY_RY(BIT, C, S)                                                  \
  { _Pragma("unroll")                                                        \
    for (int i = 0; i < 16; ++i) {                                           \
      if (!(i & (BIT))) {                                                    \
        const int j = i | (BIT);                                             \
        float ar = re[i], ai = im[i], br = re[j], bi = im[j];                \
        re[i] = fmaf((C), ar, -(S) * br);                                    \
        im[i] = fmaf((C), ai, -(S) * bi);                                    \
        re[j] = fmaf((S), ar, (C) * br);                                     \
        im[j] = fmaf((S), ai, (C) * bi);                                     \
      }                                                                      \
    } }

#define APPLY_RZ(BIT, C, S)                                                  \
  { _Pragma("unroll")                                                        \
    for (int i = 0; i < 16; ++i) {                                           \
      float vr = re[i], vi = im[i];                                          \
      if (!(i & (BIT))) { re[i] = fmaf((C), vr, (S) * vi);                   \
                          im[i] = fmaf((C), vi, -(S) * vr); }                \
      else              { re[i] = fmaf((C), vr, -(S) * vi);                  \
                          im[i] = fmaf((C), vi, (S) * vr); }                 \
    } }

#define APPLY_CNOT(CB, TB)                                                   \
  { _Pragma("unroll")                                                        \
    for (int i = 0; i < 16; ++i) {                                           \
      if ((i & (CB)) && !(i & (TB))) {                                       \
        const int j = i | (TB);                                              \
        float t = re[i]; re[i] = re[j]; re[j] = t;                           \
        t = im[i]; im[i] = im[j]; im[j] = t;                                 \
      }                                                                      \
    } }

// ---------------- main fused kernel: 1 wave / block, 16 rows, full K ----------------
__global__ __launch_bounds__(64) void qfc_mfma(
    const float* __restrict__ x,            // [16384,1280]
    const unsigned short* __restrict__ wf,  // W1 frags (prep_w1)
    const float* __restrict__ b1, const float* __restrict__ W2,
    const float* __restrict__ b2, const float* __restrict__ qw,
    const float* __restrict__ Wc1, const float* __restrict__ bc1,
    const float* __restrict__ Wc2, const float* __restrict__ bc2,
    float* __restrict__ out) {
  const int l    = threadIdx.x;  // 0..63
  const int r0   = blockIdx.x * 16;
  const int arow = l & 15;
  const int kg   = l >> 4;  // 0..3

  const float* xp = x + (size_t)(r0 + arow) * 1280 + kg * 8;
  const s16x8* bw = (const s16x8*)wf;

  f32x4 acc[4];
#pragma unroll
  for (int nt = 0; nt < 4; ++nt) acc[nt] = (f32x4)(0.f);

  float4 apf[4][2];  // A prefetch, 4 chunks deep
  s16x8  bpf[2][8];  // B frags, 2 chunks deep: [par][nt*2+sel]

#define LOAD_A(STG, C)                                        \
  { const float* p_ = xp + (C) * 32;                          \
    apf[STG][0] = *(const float4*)(p_);                       \
    apf[STG][1] = *(const float4*)(p_ + 4); }

#define LOAD_B(PAR, C)                                        \
  { const s16x8* bp_ = bw + (size_t)(C) * 512 + l;            \
    _Pragma("unroll")                                         \
    for (int q_ = 0; q_ < 8; ++q_) bpf[PAR][q_] = bp_[q_ * 64]; }

  LOAD_A(0, 0) LOAD_A(1, 1) LOAD_A(2, 2) LOAD_A(3, 3)
  LOAD_B(0, 0) LOAD_B(1, 1)

  for (int blk = 0; blk < 10; ++blk) {
#pragma unroll
    for (int u = 0; u < 4; ++u) {
      const int c = blk * 4 + u;
      // convert A chunk (registers) -> hi/lo bf16 frags
      float f[8];
      f[0] = apf[u][0].x; f[1] = apf[u][0].y; f[2] = apf[u][0].z; f[3] = apf[u][0].w;
      f[4] = apf[u][1].x; f[5] = apf[u][1].y; f[6] = apf[u][1].z; f[7] = apf[u][1].w;
      s16x8 ah, al;
#pragma unroll
      for (int j = 0; j < 8; ++j) {
        short h = f2bf_rne(f[j]);
        ah[j] = h;
        al[j] = (short)(__float_as_uint(f[j] - bf2f(h)) >> 16);  // trunc ok for lo
      }
      if (blk < 9) LOAD_A(u, c + 4)

      // 12 MFMA: xh*wh + xl*wh + xh*wl  (product-major for dep spacing)
#pragma unroll
      for (int nt = 0; nt < 4; ++nt)
        acc[nt] = __builtin_amdgcn_mfma_f32_16x16x32_bf16(ah, bpf[u & 1][nt * 2], acc[nt], 0, 0, 0);
#pragma unroll
      for (int nt = 0; nt < 4; ++nt)
        acc[nt] = __builtin_amdgcn_mfma_f32_16x16x32_bf16(al, bpf[u & 1][nt * 2], acc[nt], 0, 0, 0);
#pragma unroll
      for (int nt = 0; nt < 4; ++nt)
        acc[nt] = __builtin_amdgcn_mfma_f32_16x16x32_bf16(ah, bpf[u & 1][nt * 2 + 1], acc[nt], 0, 0, 0);

      if (blk < 9 || u < 2) LOAD_B(u & 1, c + 2)
    }
  }

  // ---- tail: D row_local = kg*4+q, col = nt*16+arow (m89-verified C/D map) ----
  float p[4][4];
#pragma unroll
  for (int q = 0; q < 4; ++q)
#pragma unroll
    for (int t = 0; t < 4; ++t) p[q][t] = 0.f;

#pragma unroll
  for (int nt = 0; nt < 4; ++nt) {
    const int cidx = nt * 16 + arow;
    const float b1c = b1[cidx];
    const float4 w2 = *(const float4*)(W2 + cidx * 4);
#pragma unroll
    for (int q = 0; q < 4; ++q) {
      float hv = fmaxf(acc[nt][q] + b1c, 0.f);
      p[q][0] = fmaf(hv, w2.x, p[q][0]);
      p[q][1] = fmaf(hv, w2.y, p[q][1]);
      p[q][2] = fmaf(hv, w2.z, p[q][2]);
      p[q][3] = fmaf(hv, w2.w, p[q][3]);
    }
  }
  // butterfly over the 16 lanes sharing kg
#pragma unroll
  for (int m = 1; m < 16; m <<= 1)
#pragma unroll
    for (int q = 0; q < 4; ++q)
#pragma unroll
      for (int t = 0; t < 4; ++t) p[q][t] += __shfl_xor(p[q][t], m);

  // lane handles row r0 + kg*4 + (l&3); select p[l&3][*] via static cndmask chain
  const int qsel = l & 3;
  float red[4];
#pragma unroll
  for (int t = 0; t < 4; ++t) {
    float v = p[0][t];
    v = (qsel == 1) ? p[1][t] : v;
    v = (qsel == 2) ? p[2][t] : v;
    v = (qsel == 3) ? p[3][t] : v;
    red[t] = tanhf(v + b2[t]);
  }

  // ---- 4-qubit statevector in registers ----
  float re[16], im[16];
#pragma unroll
  for (int i = 0; i < 16; ++i) { re[i] = 0.f; im[i] = 0.f; }
  re[0] = 1.f;
  {
    float s0, c0; sincosf(0.5f * red[0], &s0, &c0); APPLY_RY(8, c0, s0);
    float s1, c1; sincosf(0.5f * red[1], &s1, &c1); APPLY_RY(4, c1, s1);
    float s2, c2; sincosf(0.5f * red[2], &s2, &c2); APPLY_RY(2, c2, s2);
    float s3, c3; sincosf(0.5f * red[3], &s3, &c3); APPLY_RY(1, c3, s3);
  }
  for (int lyr = 0; lyr < 3; ++lyr) {
    const float* ql = qw + lyr * 8;
    { float sn, cn; sincosf(0.5f * ql[0], &sn, &cn); APPLY_RY(8, cn, sn); }
    { float sn, cn; sincosf(0.5f * ql[1], &sn, &cn); APPLY_RZ(8, cn, sn); }
    { float sn, cn; sincosf(0.5f * ql[2], &sn, &cn); APPLY_RY(4, cn, sn); }
    { float sn, cn; sincosf(0.5f * ql[3], &sn, &cn); APPLY_RZ(4, cn, sn); }
    { float sn, cn; sincosf(0.5f * ql[4], &sn, &cn); APPLY_RY(2, cn, sn); }
    { float sn, cn; sincosf(0.5f * ql[5], &sn, &cn); APPLY_RZ(2, cn, sn); }
    { float sn, cn; sincosf(0.5f * ql[6], &sn, &cn); APPLY_RY(1, cn, sn); }
    { float sn, cn; sincosf(0.5f * ql[7], &sn, &cn); APPLY_RZ(1, cn, sn); }
    APPLY_CNOT(8, 4);
    APPLY_CNOT(4, 2);
    APPLY_CNOT(2, 1);
    APPLY_CNOT(1, 8);
  }
  float q0 = 0.f, q1 = 0.f, q2 = 0.f, q3 = 0.f;
#pragma unroll
  for (int i = 0; i < 16; ++i) {
    const float pr = fmaf(re[i], re[i], im[i] * im[i]);
    q0 += (i & 8) ? -pr : pr;
    q1 += (i & 4) ? -pr : pr;
    q2 += (i & 2) ? -pr : pr;
    q3 += (i & 1) ? -pr : pr;
  }

  float logit = bc2[0];
#pragma unroll
  for (int j = 0; j < 16; ++j) {
    float a = bc1[j];
    a = fmaf(red[0], Wc1[j],       a);
    a = fmaf(red[1], Wc1[16 + j],  a);
    a = fmaf(red[2], Wc1[32 + j],  a);
    a = fmaf(red[3], Wc1[48 + j],  a);
    a = fmaf(q0,     Wc1[64 + j],  a);
    a = fmaf(q1,     Wc1[80 + j],  a);
    a = fmaf(q2,     Wc1[96 + j],  a);
    a = fmaf(q3,     Wc1[112 + j], a);
    logit = fmaf(fmaxf(a, 0.f), Wc2[j], logit);
  }
  if ((l & 12) == 0) out[r0 + kg * 4 + qsel] = logit;
}

// ---------------- fallback (round-1 kernel, known-good 87us) ----------------
#define NKT 20
__global__ __launch_bounds__(256) void qfc_fused(
    const float* __restrict__ x, const float* __restrict__ W1,
    const float* __restrict__ b1, const float* __restrict__ W2,
    const float* __restrict__ b2, const float* __restrict__ qw,
    const float* __restrict__ Wc1, const float* __restrict__ bc1,
    const float* __restrict__ Wc2, const float* __restrict__ bc2,
    float* __restrict__ out) {
  __shared__ float lds[16384];
  const int tid = threadIdx.x;
  const int lane = tid & 63;
  const int wv = tid >> 6;
  const int rg = lane >> 3;
  const int cg = lane & 7;
  const int r0 = blockIdx.x * 64;
  float acc[8][8];
#pragma unroll
  for (int i = 0; i < 8; ++i)
#pragma unroll
    for (int j = 0; j < 8; ++j) acc[i][j] = 0.f;
  const float* xrow = x + (size_t)(r0 + lane) * 1280 + wv * 16;
  const int aBase = wv * 1024;
  const int bBase = 8192 + wv * 1024;
  float4 a_st[4], b_st[4];
  auto issue_loads = [&](int kt) {
    const float* ap = xrow + kt * 64;
#pragma unroll
    for (int i = 0; i < 4; ++i) a_st[i] = *(const float4*)(ap + i * 4);
    const float* bp = W1 + kt * 4096 + wv * 1024 + lane * 4;
#pragma unroll
    for (int i = 0; i < 4; ++i) b_st[i] = *(const float4*)(bp + i * 256);
  };
  auto write_stage = [&](int buf) {
    float* A = &lds[buf * 4096 + aBase];
#pragma unroll
    for (int i = 0; i < 4; ++i) {
      float* p = A + i * 256 + lane;
      p[0] = a_st[i].x; p[64] = a_st[i].y; p[128] = a_st[i].z; p[192] = a_st[i].w;
    }
    float* Bp = &lds[buf * 4096 + bBase + lane * 4];
#pragma unroll
    for (int i = 0; i < 4; ++i) *(float4*)(Bp + i * 256) = b_st[i];
  };
  auto compute_tile = [&](int buf) {
#pragma unroll
    for (int m = 0; m < 16; ++m) {
      const float* Ak = &lds[buf * 4096 + aBase + m * 64];
      const float* Bk = &lds[buf * 4096 + bBase + m * 64];
      const float4 a0 = *(const float4*)(Ak + rg * 8);
      const float4 a1 = *(const float4*)(Ak + rg * 8 + 4);
      const float4 c0 = *(const float4*)(Bk + cg * 8);
      const float4 c1 = *(const float4*)(Bk + cg * 8 + 4);
      const float av[8] = {a0.x, a0.y, a0.z, a0.w, a1.x, a1.y, a1.z, a1.w};
      const float bv[8] = {c0.x, c0.y, c0.z, c0.w, c1.x, c1.y, c1.z, c1.w};
#pragma unroll
      for (int i = 0; i < 8; ++i)
#pragma unroll
        for (int j = 0; j < 8; ++j) acc[i][j] = fmaf(av[i], bv[j], acc[i][j]);
    }
  };
  issue_loads(0);
  write_stage(0);
  for (int kt = 0; kt < NKT; ++kt) {
    const int buf = kt & 1;
    if (kt + 1 < NKT) issue_loads(kt + 1);
    compute_tile(buf);
    if (kt + 1 < NKT) write_stage(buf ^ 1);
  }
  __syncthreads();
#pragma unroll
  for (int j = 0; j < 8; ++j) {
    const int c = cg * 8 + j;
    float* p = &lds[wv * 4096 + c * 64 + rg * 8];
    *(float4*)p = make_float4(acc[0][j], acc[1][j], acc[2][j], acc[3][j]);
    *(float4*)(p + 4) = make_float4(acc[4][j], acc[5][j], acc[6][j], acc[7][j]);
  }
  __syncthreads();
  const int s = tid >> 2;
  const int cq = tid & 3;
  float h4[4] = {0.f, 0.f, 0.f, 0.f};
#pragma unroll
  for (int cc = 0; cc < 16; ++cc) {
    const int c = cq * 16 + cc;
    const int o = c * 64 + s;
    float pp = (lds[o] + lds[4096 + o]) + (lds[8192 + o] + lds[12288 + o]);
    float hv = fmaxf(pp + b1[c], 0.f);
    const float4 w2 = *(const float4*)(W2 + c * 4);
    h4[0] = fmaf(hv, w2.x, h4[0]);
    h4[1] = fmaf(hv, w2.y, h4[1]);
    h4[2] = fmaf(hv, w2.z, h4[2]);
    h4[3] = fmaf(hv, w2.w, h4[3]);
  }
#pragma unroll
  for (int k = 0; k < 4; ++k) {
    h4[k] += __shfl_xor(h4[k], 1);
    h4[k] += __shfl_xor(h4[k], 2);
  }
  float red[4];
#pragma unroll
  for (int k = 0; k < 4; ++k) red[k] = tanhf(h4[k] + b2[k]);
  float re[16], im[16];
#pragma unroll
  for (int i = 0; i < 16; ++i) { re[i] = 0.f; im[i] = 0.f; }
  re[0] = 1.f;
  {
    float s0, c0; sincosf(0.5f * red[0], &s0, &c0); APPLY_RY(8, c0, s0);
    float s1, c1; sincosf(0.5f * red[1], &s1, &c1); APPLY_RY(4, c1, s1);
    float s2, c2; sincosf(0.5f * red[2], &s2, &c2); APPLY_RY(2, c2, s2);
    float s3, c3; sincosf(0.5f * red[3], &s3, &c3); APPLY_RY(1, c3, s3);
  }
  for (int lyr = 0; lyr < 3; ++lyr) {
    const float* ql = qw + lyr * 8;
    { float sn, cn; sincosf(0.5f * ql[0], &sn, &cn); APPLY_RY(8, cn, sn); }
    { float sn, cn; sincosf(0.5f * ql[1], &sn, &cn); APPLY_RZ(8, cn, sn); }
    { float sn, cn; sincosf(0.5f * ql[2], &sn, &cn); APPLY_RY(4, cn, sn); }
    { float sn, cn; sincosf(0.5f * ql[3], &sn, &cn); APPLY_RZ(4, cn, sn); }
    { float sn, cn; sincosf(0.5f * ql[4], &sn, &cn); APPLY_RY(2, cn, sn); }
    { float sn, cn; sincosf(0.5f * ql[5], &sn, &cn); APPLY_RZ(2, cn, sn); }
    { float sn, cn; sincosf(0.5f * ql[6], &sn, &cn); APPLY_RY(1, cn, sn); }
    { float sn, cn; sincosf(0.5f * ql[7], &sn, &cn); APPLY_RZ(1, cn, sn); }
    APPLY_CNOT(8, 4);
    APPLY_CNOT(4, 2);
    APPLY_CNOT(2, 1);
    APPLY_CNOT(1, 8);
  }
  float q0 = 0.f, q1 = 0.f, q2 = 0.f, q3 = 0.f;
#pragma unroll
  for (int i = 0; i < 16; ++i) {
    const float pr = fmaf(re[i], re[i], im[i] * im[i]);
    q0 += (i & 8) ? -pr : pr;
    q1 += (i & 4) ? -pr : pr;
    q2 += (i & 2) ? -pr : pr;
    q3 += (i & 1) ? -pr : pr;
  }
  float logit = bc2[0];
#pragma unroll
  for (int j = 0; j < 16; ++j) {
    float a = bc1[j];
    a = fmaf(red[0], Wc1[j],       a);
    a = fmaf(red[1], Wc1[16 + j],  a);
    a = fmaf(red[2], Wc1[32 + j],  a);
    a = fmaf(red[3], Wc1[48 + j],  a);
    a = fmaf(q0,     Wc1[64 + j],  a);
    a = fmaf(q1,     Wc1[80 + j],  a);
    a = fmaf(q2,     Wc1[96 + j],  a);
    a = fmaf(q3,     Wc1[112 + j], a);
    logit = fmaf(fmaxf(a, 0.f), Wc2[j], logit);
  }
  if (cq == 0) out[r0 + s] = logit;
}

extern "C" void kernel_launch(void* const* d_in, const int* in_sizes, int n_in,
                              void* d_out, int out_size, void* d_ws, size_t ws_size,
                              hipStream_t stream) {
  const float* x   = (const float*)d_in[0];
  const float* W1  = (const float*)d_in[1];
  const float* b1  = (const float*)d_in[2];
  const float* W2  = (const float*)d_in[3];
  const float* b2  = (const float*)d_in[4];
  const float* qw  = (const float*)d_in[5];
  const float* Wc1 = (const float*)d_in[6];
  const float* bc1 = (const float*)d_in[7];
  const float* Wc2 = (const float*)d_in[8];
  const float* bc2 = (const float*)d_in[9];

  if (ws_size >= 327680) {
    unsigned short* wf = (unsigned short*)d_ws;
    prep_w1<<<dim3(40), dim3(256), 0, stream>>>(W1, wf);
    qfc_mfma<<<dim3(1024), dim3(64), 0, stream>>>(
        x, wf, b1, W2, b2, qw, Wc1, bc1, Wc2, bc2, (float*)d_out);
  } else {
    qfc_fused<<<dim3(256), dim3(256), 0, stream>>>(
        x, W1, b1, W2, b2, qw, Wc1, bc1, Wc2, bc2, (float*)d_out);
  }
}

// Round 8
// 40.519 us; speedup vs baseline: 1.2524x; 1.2524x over previous
//
#include <hip/hip_runtime.h>
#include <math.h>

typedef __attribute__((ext_vector_type(4))) float f32x4;
typedef __attribute__((ext_vector_type(8))) short s16x8;

__device__ __forceinline__ short f2bf_rne(float f) {
  unsigned u = __float_as_uint(f);
  unsigned r = u + 0x7FFFu + ((u >> 16) & 1u);
  return (short)(r >> 16);
}
__device__ __forceinline__ float bf2f(short b) {
  return __uint_as_float(((unsigned)(unsigned short)b) << 16);
}

// ---------------- W1 -> bf16 hi/lo fragment pre-pack ----------------
// frag element j of lane l holds k = chunk*32 + (l>>4)*8 + j, col = nt*16 + (l&15)
// ws layout: slot = (chunk*4 + nt)*2 + sel (0=hi,1=lo); frag addr = (slot*64 + l)*8 ushorts
__global__ __launch_bounds__(256) void prep_w1(const float* __restrict__ W1,
                                               unsigned short* __restrict__ wf) {
  const int c   = blockIdx.x;         // k-chunk 0..39
  const int l   = threadIdx.x & 63;
  const int nt  = threadIdx.x >> 6;   // 0..3
  const int kb  = c * 32 + (l >> 4) * 8;
  const int col = nt * 16 + (l & 15);
  s16x8 hi, lo;
#pragma unroll
  for (int j = 0; j < 8; ++j) {
    float f = W1[(kb + j) * 64 + col];
    short h = f2bf_rne(f);
    hi[j] = h;
    lo[j] = f2bf_rne(f - bf2f(h));
  }
  const int slot = (c * 4 + nt) * 2;
  *(s16x8*)(wf + (size_t)(slot * 64 + l) * 8)       = hi;
  *(s16x8*)(wf + (size_t)((slot + 1) * 64 + l) * 8) = lo;
}

// ---------------- circuit macros (verified rounds 1-7) ----------------
#define APPLY_RY(BIT, C, S)                                                  \
  { _Pragma("unroll")                                                        \
    for (int i = 0; i < 16; ++i) {                                           \
      if (!(i & (BIT))) {                                                    \
        const int j = i | (BIT);                                             \
        float ar = re[i], ai = im[i], br = re[j], bi = im[j];                \
        re[i] = fmaf((C), ar, -(S) * br);                                    \
        im[i] = fmaf((C), ai, -(S) * bi);                                    \
        re[j] = fmaf((S), ar, (C) * br);                                     \
        im[j] = fmaf((S), ai, (C) * bi);                                     \
      }                                                                      \
    } }

#define APPLY_RZ(BIT, C, S)                                                  \
  { _Pragma("unroll")                                                        \
    for (int i = 0; i < 16; ++i) {                                           \
      float vr = re[i], vi = im[i];                                          \
      if (!(i & (BIT))) { re[i] = fmaf((C), vr, (S) * vi);                   \
                          im[i] = fmaf((C), vi, -(S) * vr); }                \
      else              { re[i] = fmaf((C), vr, -(S) * vi);                  \
                          im[i] = fmaf((C), vi, (S) * vr); }                 \
    } }

#define APPLY_CNOT(CB, TB)                                                   \
  { _Pragma("unroll")                                                        \
    for (int i = 0; i < 16; ++i) {                                           \
      if ((i & (CB)) && !(i & (TB))) {                                       \
        const int j = i | (TB);                                              \
        float t = re[i]; re[i] = re[j]; re[j] = t;                           \
        t = im[i]; im[i] = im[j]; im[j] = t;                                 \
      }                                                                      \
    } }

// ------------- main fused kernel: 4 waves/block, wave-level K-split -------------
// Block: 16 rows. Wave w: k in [w*320, w*320+320) = 10 chunks of K=32.
// 4096 waves total = 16 waves/CU. Barrier-free main loop; one LDS reduction.
__global__ __launch_bounds__(256) void qfc_mfma4(
    const float* __restrict__ x,            // [16384,1280]
    const unsigned short* __restrict__ wf,  // W1 frags (prep_w1)
    const float* __restrict__ b1, const float* __restrict__ W2,
    const float* __restrict__ b2, const float* __restrict__ qw,
    const float* __restrict__ Wc1, const float* __restrict__ bc1,
    const float* __restrict__ Wc2, const float* __restrict__ bc2,
    float* __restrict__ out) {
  // part[wv][col][row]: wv*1024 + col*16 + row, 4x64x16 floats = 16KB
  __shared__ float lds[4096];

  const int tid  = threadIdx.x;
  const int l    = tid & 63;
  const int wv   = tid >> 6;   // k-quarter owner
  const int r0   = blockIdx.x * 16;
  const int arow = l & 15;
  const int kg   = l >> 4;     // 0..3

  const float* xp = x + (size_t)(r0 + arow) * 1280 + wv * 320 + kg * 8;
  const s16x8* bw = (const s16x8*)wf + (size_t)wv * 5120 + l;  // wave's 10 chunks

  f32x4 acc[4];
#pragma unroll
  for (int nt = 0; nt < 4; ++nt) acc[nt] = (f32x4)(0.f);

  float4 apf[4][2];  // A prefetch, 4 chunks deep
  s16x8  bpf[2][8];  // B frags, 2 chunks deep

#define LOAD_A(STG, C)                                        \
  { const float* p_ = xp + (C) * 32;                          \
    apf[STG][0] = *(const float4*)(p_);                       \
    apf[STG][1] = *(const float4*)(p_ + 4); }

#define LOAD_B(PAR, C)                                        \
  { const s16x8* bp_ = bw + (C) * 512;                        \
    _Pragma("unroll")                                         \
    for (int q_ = 0; q_ < 8; ++q_) bpf[PAR][q_] = bp_[q_ * 64]; }

  LOAD_A(0, 0) LOAD_A(1, 1) LOAD_A(2, 2) LOAD_A(3, 3)
  LOAD_B(0, 0) LOAD_B(1, 1)

#pragma unroll
  for (int c = 0; c < 10; ++c) {
    // convert A chunk (registers) -> hi/lo bf16 frags
    float f[8];
    f[0] = apf[c & 3][0].x; f[1] = apf[c & 3][0].y;
    f[2] = apf[c & 3][0].z; f[3] = apf[c & 3][0].w;
    f[4] = apf[c & 3][1].x; f[5] = apf[c & 3][1].y;
    f[6] = apf[c & 3][1].z; f[7] = apf[c & 3][1].w;
    s16x8 ah, al;
#pragma unroll
    for (int j = 0; j < 8; ++j) {
      short h = f2bf_rne(f[j]);
      ah[j] = h;
      al[j] = (short)(__float_as_uint(f[j] - bf2f(h)) >> 16);  // trunc ok for lo
    }
    if (c + 4 < 10) LOAD_A(c & 3, c + 4)

    // 12 MFMA: xh*wh + xl*wh + xh*wl
#pragma unroll
    for (int nt = 0; nt < 4; ++nt)
      acc[nt] = __builtin_amdgcn_mfma_f32_16x16x32_bf16(ah, bpf[c & 1][nt * 2], acc[nt], 0, 0, 0);
#pragma unroll
    for (int nt = 0; nt < 4; ++nt)
      acc[nt] = __builtin_amdgcn_mfma_f32_16x16x32_bf16(al, bpf[c & 1][nt * 2], acc[nt], 0, 0, 0);
#pragma unroll
    for (int nt = 0; nt < 4; ++nt)
      acc[nt] = __builtin_amdgcn_mfma_f32_16x16x32_bf16(ah, bpf[c & 1][nt * 2 + 1], acc[nt], 0, 0, 0);

    if (c + 2 < 10) LOAD_B(c & 1, c + 2)
  }
#undef LOAD_A
#undef LOAD_B

  // ---- k-partial handoff: acc[nt][q] = Dpart[row kg*4+q][col nt*16+arow] ----
#pragma unroll
  for (int nt = 0; nt < 4; ++nt)
    *(float4*)&lds[wv * 1024 + (nt * 16 + arow) * 16 + kg * 4] =
        make_float4(acc[nt][0], acc[nt][1], acc[nt][2], acc[nt][3]);
  __syncthreads();

  // ---- fused tail: wave 0 only, 4 threads per sample (16 samples) ----
  if (tid < 64) {
    const int s  = tid >> 2;  // sample 0..15
    const int cq = tid & 3;   // c-quarter (16 cols each)

    float h4[4] = {0.f, 0.f, 0.f, 0.f};
#pragma unroll
    for (int cc = 0; cc < 16; ++cc) {
      const int c = cq * 16 + cc;
      const int o = c * 16 + s;
      float p  = (lds[o] + lds[1024 + o]) + (lds[2048 + o] + lds[3072 + o]);
      float hv = fmaxf(p + b1[c], 0.f);
      const float4 w2 = *(const float4*)(W2 + c * 4);
      h4[0] = fmaf(hv, w2.x, h4[0]);
      h4[1] = fmaf(hv, w2.y, h4[1]);
      h4[2] = fmaf(hv, w2.z, h4[2]);
      h4[3] = fmaf(hv, w2.w, h4[3]);
    }
#pragma unroll
    for (int k = 0; k < 4; ++k) {
      h4[k] += __shfl_xor(h4[k], 1);
      h4[k] += __shfl_xor(h4[k], 2);
    }

    float red[4];
#pragma unroll
    for (int k = 0; k < 4; ++k) red[k] = tanhf(h4[k] + b2[k]);

    // ---- 4-qubit statevector in registers ----
    float re[16], im[16];
#pragma unroll
    for (int i = 0; i < 16; ++i) { re[i] = 0.f; im[i] = 0.f; }
    re[0] = 1.f;
    {
      float s0, c0; sincosf(0.5f * red[0], &s0, &c0); APPLY_RY(8, c0, s0);
      float s1, c1; sincosf(0.5f * red[1], &s1, &c1); APPLY_RY(4, c1, s1);
      float s2, c2; sincosf(0.5f * red[2], &s2, &c2); APPLY_RY(2, c2, s2);
      float s3, c3; sincosf(0.5f * red[3], &s3, &c3); APPLY_RY(1, c3, s3);
    }
    for (int lyr = 0; lyr < 3; ++lyr) {
      const float* ql = qw + lyr * 8;
      { float sn, cn; sincosf(0.5f * ql[0], &sn, &cn); APPLY_RY(8, cn, sn); }
      { float sn, cn; sincosf(0.5f * ql[1], &sn, &cn); APPLY_RZ(8, cn, sn); }
      { float sn, cn; sincosf(0.5f * ql[2], &sn, &cn); APPLY_RY(4, cn, sn); }
      { float sn, cn; sincosf(0.5f * ql[3], &sn, &cn); APPLY_RZ(4, cn, sn); }
      { float sn, cn; sincosf(0.5f * ql[4], &sn, &cn); APPLY_RY(2, cn, sn); }
      { float sn, cn; sincosf(0.5f * ql[5], &sn, &cn); APPLY_RZ(2, cn, sn); }
      { float sn, cn; sincosf(0.5f * ql[6], &sn, &cn); APPLY_RY(1, cn, sn); }
      { float sn, cn; sincosf(0.5f * ql[7], &sn, &cn); APPLY_RZ(1, cn, sn); }
      APPLY_CNOT(8, 4);
      APPLY_CNOT(4, 2);
      APPLY_CNOT(2, 1);
      APPLY_CNOT(1, 8);
    }
    float q0 = 0.f, q1 = 0.f, q2 = 0.f, q3 = 0.f;
#pragma unroll
    for (int i = 0; i < 16; ++i) {
      const float pr = fmaf(re[i], re[i], im[i] * im[i]);
      q0 += (i & 8) ? -pr : pr;
      q1 += (i & 4) ? -pr : pr;
      q2 += (i & 2) ? -pr : pr;
      q3 += (i & 1) ? -pr : pr;
    }

    float logit = bc2[0];
#pragma unroll
    for (int j = 0; j < 16; ++j) {
      float a = bc1[j];
      a = fmaf(red[0], Wc1[j],       a);
      a = fmaf(red[1], Wc1[16 + j],  a);
      a = fmaf(red[2], Wc1[32 + j],  a);
      a = fmaf(red[3], Wc1[48 + j],  a);
      a = fmaf(q0,     Wc1[64 + j],  a);
      a = fmaf(q1,     Wc1[80 + j],  a);
      a = fmaf(q2,     Wc1[96 + j],  a);
      a = fmaf(q3,     Wc1[112 + j], a);
      logit = fmaf(fmaxf(a, 0.f), Wc2[j], logit);
    }
    if (cq == 0) out[r0 + s] = logit;
  }
}

// ---------------- fallback (round-1 kernel, known-good) ----------------
#define NKT 20
__global__ __launch_bounds__(256) void qfc_fused(
    const float* __restrict__ x, const float* __restrict__ W1,
    const float* __restrict__ b1, const float* __restrict__ W2,
    const float* __restrict__ b2, const float* __restrict__ qw,
    const float* __restrict__ Wc1, const float* __restrict__ bc1,
    const float* __restrict__ Wc2, const float* __restrict__ bc2,
    float* __restrict__ out) {
  __shared__ float lds[16384];
  const int tid = threadIdx.x;
  const int lane = tid & 63;
  const int wv = tid >> 6;
  const int rg = lane >> 3;
  const int cg = lane & 7;
  const int r0 = blockIdx.x * 64;
  float acc[8][8];
#pragma unroll
  for (int i = 0; i < 8; ++i)
#pragma unroll
    for (int j = 0; j < 8; ++j) acc[i][j] = 0.f;
  const float* xrow = x + (size_t)(r0 + lane) * 1280 + wv * 16;
  const int aBase = wv * 1024;
  const int bBase = 8192 + wv * 1024;
  float4 a_st[4], b_st[4];
  auto issue_loads = [&](int kt) {
    const float* ap = xrow + kt * 64;
#pragma unroll
    for (int i = 0; i < 4; ++i) a_st[i] = *(const float4*)(ap + i * 4);
    const float* bp = W1 + kt * 4096 + wv * 1024 + lane * 4;
#pragma unroll
    for (int i = 0; i < 4; ++i) b_st[i] = *(const float4*)(bp + i * 256);
  };
  auto write_stage = [&](int buf) {
    float* A = &lds[buf * 4096 + aBase];
#pragma unroll
    for (int i = 0; i < 4; ++i) {
      float* p = A + i * 256 + lane;
      p[0] = a_st[i].x; p[64] = a_st[i].y; p[128] = a_st[i].z; p[192] = a_st[i].w;
    }
    float* Bp = &lds[buf * 4096 + bBase + lane * 4];
#pragma unroll
    for (int i = 0; i < 4; ++i) *(float4*)(Bp + i * 256) = b_st[i];
  };
  auto compute_tile = [&](int buf) {
#pragma unroll
    for (int m = 0; m < 16; ++m) {
      const float* Ak = &lds[buf * 4096 + aBase + m * 64];
      const float* Bk = &lds[buf * 4096 + bBase + m * 64];
      const float4 a0 = *(const float4*)(Ak + rg * 8);
      const float4 a1 = *(const float4*)(Ak + rg * 8 + 4);
      const float4 c0 = *(const float4*)(Bk + cg * 8);
      const float4 c1 = *(const float4*)(Bk + cg * 8 + 4);
      const float av[8] = {a0.x, a0.y, a0.z, a0.w, a1.x, a1.y, a1.z, a1.w};
      const float bv[8] = {c0.x, c0.y, c0.z, c0.w, c1.x, c1.y, c1.z, c1.w};
#pragma unroll
      for (int i = 0; i < 8; ++i)
#pragma unroll
        for (int j = 0; j < 8; ++j) acc[i][j] = fmaf(av[i], bv[j], acc[i][j]);
    }
  };
  issue_loads(0);
  write_stage(0);
  for (int kt = 0; kt < NKT; ++kt) {
    const int buf = kt & 1;
    if (kt + 1 < NKT) issue_loads(kt + 1);
    compute_tile(buf);
    if (kt + 1 < NKT) write_stage(buf ^ 1);
  }
  __syncthreads();
#pragma unroll
  for (int j = 0; j < 8; ++j) {
    const int c = cg * 8 + j;
    float* p = &lds[wv * 4096 + c * 64 + rg * 8];
    *(float4*)p = make_float4(acc[0][j], acc[1][j], acc[2][j], acc[3][j]);
    *(float4*)(p + 4) = make_float4(acc[4][j], acc[5][j], acc[6][j], acc[7][j]);
  }
  __syncthreads();
  const int s = tid >> 2;
  const int cq = tid & 3;
  float h4[4] = {0.f, 0.f, 0.f, 0.f};
#pragma unroll
  for (int cc = 0; cc < 16; ++cc) {
    const int c = cq * 16 + cc;
    const int o = c * 64 + s;
    float pp = (lds[o] + lds[4096 + o]) + (lds[8192 + o] + lds[12288 + o]);
    float hv = fmaxf(pp + b1[c], 0.f);
    const float4 w2 = *(const float4*)(W2 + c * 4);
    h4[0] = fmaf(hv, w2.x, h4[0]);
    h4[1] = fmaf(hv, w2.y, h4[1]);
    h4[2] = fmaf(hv, w2.z, h4[2]);
    h4[3] = fmaf(hv, w2.w, h4[3]);
  }
#pragma unroll
  for (int k = 0; k < 4; ++k) {
    h4[k] += __shfl_xor(h4[k], 1);
    h4[k] += __shfl_xor(h4[k], 2);
  }
  float red[4];
#pragma unroll
  for (int k = 0; k < 4; ++k) red[k] = tanhf(h4[k] + b2[k]);
  float re[16], im[16];
#pragma unroll
  for (int i = 0; i < 16; ++i) { re[i] = 0.f; im[i] = 0.f; }
  re[0] = 1.f;
  {
    float s0, c0; sincosf(0.5f * red[0], &s0, &c0); APPLY_RY(8, c0, s0);
    float s1, c1; sincosf(0.5f * red[1], &s1, &c1); APPLY_RY(4, c1, s1);
    float s2, c2; sincosf(0.5f * red[2], &s2, &c2); APPLY_RY(2, c2, s2);
    float s3, c3; sincosf(0.5f * red[3], &s3, &c3); APPLY_RY(1, c3, s3);
  }
  for (int lyr = 0; lyr < 3; ++lyr) {
    const float* ql = qw + lyr * 8;
    { float sn, cn; sincosf(0.5f * ql[0], &sn, &cn); APPLY_RY(8, cn, sn); }
    { float sn, cn; sincosf(0.5f * ql[1], &sn, &cn); APPLY_RZ(8, cn, sn); }
    { float sn, cn; sincosf(0.5f * ql[2], &sn, &cn); APPLY_RY(4, cn, sn); }
    { float sn, cn; sincosf(0.5f * ql[3], &sn, &cn); APPLY_RZ(4, cn, sn); }
    { float sn, cn; sincosf(0.5f * ql[4], &sn, &cn); APPLY_RY(2, cn, sn); }
    { float sn, cn; sincosf(0.5f * ql[5], &sn, &cn); APPLY_RZ(2, cn, sn); }
    { float sn, cn; sincosf(0.5f * ql[6], &sn, &cn); APPLY_RY(1, cn, sn); }
    { float sn, cn; sincosf(0.5f * ql[7], &sn, &cn); APPLY_RZ(1, cn, sn); }
    APPLY_CNOT(8, 4);
    APPLY_CNOT(4, 2);
    APPLY_CNOT(2, 1);
    APPLY_CNOT(1, 8);
  }
  float q0 = 0.f, q1 = 0.f, q2 = 0.f, q3 = 0.f;
#pragma unroll
  for (int i = 0; i < 16; ++i) {
    const float pr = fmaf(re[i], re[i], im[i] * im[i]);
    q0 += (i & 8) ? -pr : pr;
    q1 += (i & 4) ? -pr : pr;
    q2 += (i & 2) ? -pr : pr;
    q3 += (i & 1) ? -pr : pr;
  }
  float logit = bc2[0];
#pragma unroll
  for (int j = 0; j < 16; ++j) {
    float a = bc1[j];
    a = fmaf(red[0], Wc1[j],       a);
    a = fmaf(red[1], Wc1[16 + j],  a);
    a = fmaf(red[2], Wc1[32 + j],  a);
    a = fmaf(red[3], Wc1[48 + j],  a);
    a = fmaf(q0,     Wc1[64 + j],  a);
    a = fmaf(q1,     Wc1[80 + j],  a);
    a = fmaf(q2,     Wc1[96 + j],  a);
    a = fmaf(q3,     Wc1[112 + j], a);
    logit = fmaf(fmaxf(a, 0.f), Wc2[j], logit);
  }
  if (cq == 0) out[r0 + s] = logit;
}

extern "C" void kernel_launch(void* const* d_in, const int* in_sizes, int n_in,
                              void* d_out, int out_size, void* d_ws, size_t ws_size,
                              hipStream_t stream) {
  const float* x   = (const float*)d_in[0];
  const float* W1  = (const float*)d_in[1];
  const float* b1  = (const float*)d_in[2];
  const float* W2  = (const float*)d_in[3];
  const float* b2  = (const float*)d_in[4];
  const float* qw  = (const float*)d_in[5];
  const float* Wc1 = (const float*)d_in[6];
  const float* bc1 = (const float*)d_in[7];
  const float* Wc2 = (const float*)d_in[8];
  const float* bc2 = (const float*)d_in[9];

  if (ws_size >= 327680) {
    unsigned short* wf = (unsigned short*)d_ws;
    prep_w1<<<dim3(40), dim3(256), 0, stream>>>(W1, wf);
    qfc_mfma4<<<dim3(1024), dim3(256), 0, stream>>>(
        x, wf, b1, W2, b2, qw, Wc1, bc1, Wc2, bc2, (float*)d_out);
  } else {
    qfc_fused<<<dim3(256), dim3(256), 0, stream>>>(
        x, W1, b1, W2, b2, qw, Wc1, bc1, Wc2, bc2, (float*)d_out);
  }
}

// Round 9
// 39.915 us; speedup vs baseline: 1.2714x; 1.0151x over previous
//
#include <hip/hip_runtime.h>
#include <math.h>

typedef __attribute__((ext_vector_type(4))) float f32x4;
typedef __attribute__((ext_vector_type(8))) short s16x8;

__device__ __forceinline__ short f2bf_rne(float f) {
  unsigned u = __float_as_uint(f);
  unsigned r = u + 0x7FFFu + ((u >> 16) & 1u);
  return (short)(r >> 16);
}
__device__ __forceinline__ float bf2f(short b) {
  return __uint_as_float(((unsigned)(unsigned short)b) << 16);
}

#define WAIT_VMCNT(N) asm volatile("s_waitcnt vmcnt(" #N ")" ::: "memory")
#define WAIT_LGKM0()  asm volatile("s_waitcnt lgkmcnt(0)" ::: "memory")
#define BAR()         __builtin_amdgcn_s_barrier()

__device__ __forceinline__ void gl_lds16(const void* g, void* l) {
  __builtin_amdgcn_global_load_lds(
      (const __attribute__((address_space(1))) void*)g,
      (__attribute__((address_space(3))) void*)l, 16, 0, 0);
}

// ---------------- W1 -> bf16 hi/lo fragment pre-pack (unchanged) ----------------
// frag element j of lane l holds k = chunk*32 + (l>>4)*8 + j, col = nt*16 + (l&15)
// ws layout: slot = (chunk*4 + nt)*2 + sel (0=hi,1=lo); frag addr = (slot*64 + l)*8 ushorts
__global__ __launch_bounds__(256) void prep_w1(const float* __restrict__ W1,
                                               unsigned short* __restrict__ wf) {
  const int c   = blockIdx.x;         // k-chunk 0..39
  const int l   = threadIdx.x & 63;
  const int nt  = threadIdx.x >> 6;   // 0..3
  const int kb  = c * 32 + (l >> 4) * 8;
  const int col = nt * 16 + (l & 15);
  s16x8 hi, lo;
#pragma unroll
  for (int j = 0; j < 8; ++j) {
    float f = W1[(kb + j) * 64 + col];
    short h = f2bf_rne(f);
    hi[j] = h;
    lo[j] = f2bf_rne(f - bf2f(h));
  }
  const int slot = (c * 4 + nt) * 2;
  *(s16x8*)(wf + (size_t)(slot * 64 + l) * 8)       = hi;
  *(s16x8*)(wf + (size_t)((slot + 1) * 64 + l) * 8) = lo;
}

// ---------------- circuit macros (verified rounds 1-8) ----------------
#define APPLY_RY(BIT, C, S)                                                  \
  { _Pragma("unroll")                                                        \
    for (int i = 0; i < 16; ++i) {                                           \
      if (!(i & (BIT))) {                                                    \
        const int j = i | (BIT);                                             \
        float ar = re[i], ai = im[i], br = re[j], bi = im[j];                \
        re[i] = fmaf((C), ar, -(S) * br);                                    \
        im[i] = fmaf((C), ai, -(S) * bi);                                    \
        re[j] = fmaf((S), ar, (C) * br);                                     \
        im[j] = fmaf((S), ai, (C) * bi);                                     \
      }                                                                      \
    } }

#define APPLY_RZ(BIT, C, S)                                                  \
  { _Pragma("unroll")                                                        \
    for (int i = 0; i < 16; ++i) {                                           \
      float vr = re[i], vi = im[i];                                          \
      if (!(i & (BIT))) { re[i] = fmaf((C), vr, (S) * vi);                   \
                          im[i] = fmaf((C), vi, -(S) * vr); }                \
      else              { re[i] = fmaf((C), vr, -(S) * vi);                  \
                          im[i] = fmaf((C), vi, (S) * vr); }                 \
    } }

#define APPLY_CNOT(CB, TB)                                                   \
  { _Pragma("unroll")                                                        \
    for (int i = 0; i < 16; ++i) {                                           \
      if ((i & (CB)) && !(i & (TB))) {                                       \
        const int j = i | (TB);                                              \
        float t = re[i]; re[i] = re[j]; re[j] = t;                           \
        t = im[i]; im[i] = im[j]; im[j] = t;                                 \
      }                                                                      \
    } }

// ============ Kernel A: GEMM partial, LDS-pipelined (T3/T4 pattern) ============
// Block = (row-tile rt: 64 rows, k-quarter kq: 320 k = 10 chunks of K=32).
// Wave w owns rows rt*64 + w*16 .. +16; all 4 waves share each B chunk.
// LDS: Bs dbuf 2x8KB (shared) + As dbuf 2x(4 waves x 2KB) = 32KB.
// Main loop: raw s_barrier + counted vmcnt (never 0 mid-loop), global_load_lds.
// Output: ws partial [blockIdx][col 0..63][row 0..63] f32 (4KB/block).
__global__ __launch_bounds__(256) void qfc_gemm(
    const float* __restrict__ x,            // [16384,1280]
    const unsigned short* __restrict__ wf,  // W1 frags (prep_w1)
    float* __restrict__ pw)                 // partials [1024][4096]
{
  __shared__ s16x8 Bs[2][512];     // [buf][slot*64+l] : 8KB per buf
  __shared__ float As[2][4][512];  // [buf][wave][rowpiece] : 2KB per wave per buf

  const int tid  = threadIdx.x;
  const int l    = tid & 63;
  const int wv   = tid >> 6;
  const int rt   = blockIdx.x >> 2;
  const int kq   = blockIdx.x & 3;
  const int arow = l & 15;
  const int kg   = l >> 4;  // 0..3

  // A staging source: lane l loads 16B pieces of row rt*64+wv*16+(l>>2)
  const float* xw = x + (size_t)(rt * 64 + wv * 16 + (l >> 2)) * 1280 +
                    kq * 320 + (l & 3) * 4;
  // B staging source: this kq's 10 chunks are contiguous in wf
  const s16x8* wfch = (const s16x8*)wf + (size_t)(kq * 10) * 512;

  f32x4 acc[4];
#pragma unroll
  for (int nt = 0; nt < 4; ++nt) acc[nt] = (f32x4)(0.f);

  // stage chunk c into buffer buf: per wave 2 B-gloads + 2 A-gloads (all 16B/lane)
#define STAGE(C, BUF)                                                        \
  {                                                                          \
    const s16x8* bsrc_ = wfch + (size_t)(C) * 512 + wv * 128 + l;            \
    gl_lds16(bsrc_,      &Bs[BUF][wv * 128]);                                \
    gl_lds16(bsrc_ + 64, &Bs[BUF][wv * 128 + 64]);                           \
    const float* asrc_ = xw + (C) * 32;                                      \
    gl_lds16(asrc_,      &As[BUF][wv][0]);                                   \
    gl_lds16(asrc_ + 16, &As[BUF][wv][256]);                                 \
  }

  STAGE(0, 0)
  STAGE(1, 1)

#pragma unroll
  for (int c = 0; c < 10; ++c) {
    const int buf = c & 1;
    // chunk c landed (this wave's 4 oldest gloads); 4 newer (c+1) stay in flight
    if (c < 9) { WAIT_VMCNT(4); } else { WAIT_VMCNT(0); }
    BAR();

    // ---- read A piece (row arow, k kg*8..+8) and convert to hi/lo bf16 ----
    const float* Ab = &As[buf][wv][(kg >> 1) * 256 + arow * 16 + (kg & 1) * 8];
    const float4 fa = *(const float4*)(Ab);
    const float4 fb = *(const float4*)(Ab + 4);
    float f[8] = {fa.x, fa.y, fa.z, fa.w, fb.x, fb.y, fb.z, fb.w};
    s16x8 ah, al;
#pragma unroll
    for (int j = 0; j < 8; ++j) {
      short h = f2bf_rne(f[j]);
      ah[j] = h;
      al[j] = (short)(__float_as_uint(f[j] - bf2f(h)) >> 16);  // trunc ok for lo
    }
    // ---- read shared B frags ----
    s16x8 bq[8];
#pragma unroll
    for (int q = 0; q < 8; ++q) bq[q] = Bs[buf][q * 64 + l];

    // protect buf from restaging until all waves have read it
    WAIT_LGKM0();
    if (c + 2 < 10) {
      BAR();
      STAGE(c + 2, buf)  // loads fly during the MFMAs below
    }

    // 12 MFMA: xh*wh + xl*wh + xh*wl (same order as round 8 -> same numerics)
#pragma unroll
    for (int nt = 0; nt < 4; ++nt)
      acc[nt] = __builtin_amdgcn_mfma_f32_16x16x32_bf16(ah, bq[nt * 2], acc[nt], 0, 0, 0);
#pragma unroll
    for (int nt = 0; nt < 4; ++nt)
      acc[nt] = __builtin_amdgcn_mfma_f32_16x16x32_bf16(al, bq[nt * 2], acc[nt], 0, 0, 0);
#pragma unroll
    for (int nt = 0; nt < 4; ++nt)
      acc[nt] = __builtin_amdgcn_mfma_f32_16x16x32_bf16(ah, bq[nt * 2 + 1], acc[nt], 0, 0, 0);
  }
#undef STAGE

  // ---- store partial: D row_local = kg*4+q, col = nt*16+arow ----
  float* wsp = pw + (size_t)blockIdx.x * 4096;
#pragma unroll
  for (int nt = 0; nt < 4; ++nt)
    *(float4*)(wsp + (nt * 16 + arow) * 64 + wv * 16 + kg * 4) =
        make_float4(acc[nt][0], acc[nt][1], acc[nt][2], acc[nt][3]);
}

// ============ Kernel B: combine partials + fused tail ============
// 256 blocks x 256 threads; block rt covers samples rt*64..+64, 4 threads/sample.
__global__ __launch_bounds__(256) void qfc_tail(
    const float* __restrict__ pw,   // partials [1024][4096]
    const float* __restrict__ b1, const float* __restrict__ W2,
    const float* __restrict__ b2, const float* __restrict__ qw,
    const float* __restrict__ Wc1, const float* __restrict__ bc1,
    const float* __restrict__ Wc2, const float* __restrict__ bc2,
    float* __restrict__ out) {
  const int tid = threadIdx.x;
  const int s   = tid >> 2;  // sample within tile 0..63
  const int cq  = tid & 3;   // c-quarter
  const int rt  = blockIdx.x;
  const float* base = pw + (size_t)rt * 4 * 4096;

  float h4[4] = {0.f, 0.f, 0.f, 0.f};
#pragma unroll
  for (int cc = 0; cc < 16; ++cc) {
    const int c = cq * 16 + cc;
    const int o = c * 64 + s;
    float p  = (base[o] + base[4096 + o]) + (base[8192 + o] + base[12288 + o]);
    float hv = fmaxf(p + b1[c], 0.f);
    const float4 w2 = *(const float4*)(W2 + c * 4);
    h4[0] = fmaf(hv, w2.x, h4[0]);
    h4[1] = fmaf(hv, w2.y, h4[1]);
    h4[2] = fmaf(hv, w2.z, h4[2]);
    h4[3] = fmaf(hv, w2.w, h4[3]);
  }
#pragma unroll
  for (int k = 0; k < 4; ++k) {
    h4[k] += __shfl_xor(h4[k], 1);
    h4[k] += __shfl_xor(h4[k], 2);
  }

  float red[4];
#pragma unroll
  for (int k = 0; k < 4; ++k) red[k] = tanhf(h4[k] + b2[k]);

  // ---- 4-qubit statevector in registers ----
  float re[16], im[16];
#pragma unroll
  for (int i = 0; i < 16; ++i) { re[i] = 0.f; im[i] = 0.f; }
  re[0] = 1.f;
  {
    float s0, c0; sincosf(0.5f * red[0], &s0, &c0); APPLY_RY(8, c0, s0);
    float s1, c1; sincosf(0.5f * red[1], &s1, &c1); APPLY_RY(4, c1, s1);
    float s2, c2; sincosf(0.5f * red[2], &s2, &c2); APPLY_RY(2, c2, s2);
    float s3, c3; sincosf(0.5f * red[3], &s3, &c3); APPLY_RY(1, c3, s3);
  }
  for (int lyr = 0; lyr < 3; ++lyr) {
    const float* ql = qw + lyr * 8;
    { float sn, cn; sincosf(0.5f * ql[0], &sn, &cn); APPLY_RY(8, cn, sn); }
    { float sn, cn; sincosf(0.5f * ql[1], &sn, &cn); APPLY_RZ(8, cn, sn); }
    { float sn, cn; sincosf(0.5f * ql[2], &sn, &cn); APPLY_RY(4, cn, sn); }
    { float sn, cn; sincosf(0.5f * ql[3], &sn, &cn); APPLY_RZ(4, cn, sn); }
    { float sn, cn; sincosf(0.5f * ql[4], &sn, &cn); APPLY_RY(2, cn, sn); }
    { float sn, cn; sincosf(0.5f * ql[5], &sn, &cn); APPLY_RZ(2, cn, sn); }
    { float sn, cn; sincosf(0.5f * ql[6], &sn, &cn); APPLY_RY(1, cn, sn); }
    { float sn, cn; sincosf(0.5f * ql[7], &sn, &cn); APPLY_RZ(1, cn, sn); }
    APPLY_CNOT(8, 4);
    APPLY_CNOT(4, 2);
    APPLY_CNOT(2, 1);
    APPLY_CNOT(1, 8);
  }
  float q0 = 0.f, q1 = 0.f, q2 = 0.f, q3 = 0.f;
#pragma unroll
  for (int i = 0; i < 16; ++i) {
    const float pr = fmaf(re[i], re[i], im[i] * im[i]);
    q0 += (i & 8) ? -pr : pr;
    q1 += (i & 4) ? -pr : pr;
    q2 += (i & 2) ? -pr : pr;
    q3 += (i & 1) ? -pr : pr;
  }

  float logit = bc2[0];
#pragma unroll
  for (int j = 0; j < 16; ++j) {
    float a = bc1[j];
    a = fmaf(red[0], Wc1[j],       a);
    a = fmaf(red[1], Wc1[16 + j],  a);
    a = fmaf(red[2], Wc1[32 + j],  a);
    a = fmaf(red[3], Wc1[48 + j],  a);
    a = fmaf(q0,     Wc1[64 + j],  a);
    a = fmaf(q1,     Wc1[80 + j],  a);
    a = fmaf(q2,     Wc1[96 + j],  a);
    a = fmaf(q3,     Wc1[112 + j], a);
    logit = fmaf(fmaxf(a, 0.f), Wc2[j], logit);
  }
  if (cq == 0) out[rt * 64 + s] = logit;
}

// ============ Fallback A: round-8 kernel (known-good 40.5us) ============
__global__ __launch_bounds__(256) void qfc_mfma4(
    const float* __restrict__ x, const unsigned short* __restrict__ wf,
    const float* __restrict__ b1, const float* __restrict__ W2,
    const float* __restrict__ b2, const float* __restrict__ qw,
    const float* __restrict__ Wc1, const float* __restrict__ bc1,
    const float* __restrict__ Wc2, const float* __restrict__ bc2,
    float* __restrict__ out) {
  __shared__ float lds[4096];
  const int tid  = threadIdx.x;
  const int l    = tid & 63;
  const int wv   = tid >> 6;
  const int r0   = blockIdx.x * 16;
  const int arow = l & 15;
  const int kg   = l >> 4;

  const float* xp = x + (size_t)(r0 + arow) * 1280 + wv * 320 + kg * 8;
  const s16x8* bw = (const s16x8*)wf + (size_t)wv * 5120 + l;

  f32x4 acc[4];
#pragma unroll
  for (int nt = 0; nt < 4; ++nt) acc[nt] = (f32x4)(0.f);
  float4 apf[4][2];
  s16x8  bpf[2][8];
#define LOAD_A(STG, C)                                        \
  { const float* p_ = xp + (C) * 32;                          \
    apf[STG][0] = *(const float4*)(p_);                       \
    apf[STG][1] = *(const float4*)(p_ + 4); }
#define LOAD_B(PAR, C)                                        \
  { const s16x8* bp_ = bw + (C) * 512;                        \
    _Pragma("unroll")                                         \
    for (int q_ = 0; q_ < 8; ++q_) bpf[PAR][q_] = bp_[q_ * 64]; }
  LOAD_A(0, 0) LOAD_A(1, 1) LOAD_A(2, 2) LOAD_A(3, 3)
  LOAD_B(0, 0) LOAD_B(1, 1)
#pragma unroll
  for (int c = 0; c < 10; ++c) {
    float f[8];
    f[0] = apf[c & 3][0].x; f[1] = apf[c & 3][0].y;
    f[2] = apf[c & 3][0].z; f[3] = apf[c & 3][0].w;
    f[4] = apf[c & 3][1].x; f[5] = apf[c & 3][1].y;
    f[6] = apf[c & 3][1].z; f[7] = apf[c & 3][1].w;
    s16x8 ah, al;
#pragma unroll
    for (int j = 0; j < 8; ++j) {
      short h = f2bf_rne(f[j]);
      ah[j] = h;
      al[j] = (short)(__float_as_uint(f[j] - bf2f(h)) >> 16);
    }
    if (c + 4 < 10) LOAD_A(c & 3, c + 4)
#pragma unroll
    for (int nt = 0; nt < 4; ++nt)
      acc[nt] = __builtin_amdgcn_mfma_f32_16x16x32_bf16(ah, bpf[c & 1][nt * 2], acc[nt], 0, 0, 0);
#pragma unroll
    for (int nt = 0; nt < 4; ++nt)
      acc[nt] = __builtin_amdgcn_mfma_f32_16x16x32_bf16(al, bpf[c & 1][nt * 2], acc[nt], 0, 0, 0);
#pragma unroll
    for (int nt = 0; nt < 4; ++nt)
      acc[nt] = __builtin_amdgcn_mfma_f32_16x16x32_bf16(ah, bpf[c & 1][nt * 2 + 1], acc[nt], 0, 0, 0);
    if (c + 2 < 10) LOAD_B(c & 1, c + 2)
  }
#undef LOAD_A
#undef LOAD_B
#pragma unroll
  for (int nt = 0; nt < 4; ++nt)
    *(float4*)&lds[wv * 1024 + (nt * 16 + arow) * 16 + kg * 4] =
        make_float4(acc[nt][0], acc[nt][1], acc[nt][2], acc[nt][3]);
  __syncthreads();
  if (tid < 64) {
    const int s  = tid >> 2;
    const int cq = tid & 3;
    float h4[4] = {0.f, 0.f, 0.f, 0.f};
#pragma unroll
    for (int cc = 0; cc < 16; ++cc) {
      const int c = cq * 16 + cc;
      const int o = c * 16 + s;
      float p  = (lds[o] + lds[1024 + o]) + (lds[2048 + o] + lds[3072 + o]);
      float hv = fmaxf(p + b1[c], 0.f);
      const float4 w2 = *(const float4*)(W2 + c * 4);
      h4[0] = fmaf(hv, w2.x, h4[0]);
      h4[1] = fmaf(hv, w2.y, h4[1]);
      h4[2] = fmaf(hv, w2.z, h4[2]);
      h4[3] = fmaf(hv, w2.w, h4[3]);
    }
#pragma unroll
    for (int k = 0; k < 4; ++k) {
      h4[k] += __shfl_xor(h4[k], 1);
      h4[k] += __shfl_xor(h4[k], 2);
    }
    float red[4];
#pragma unroll
    for (int k = 0; k < 4; ++k) red[k] = tanhf(h4[k] + b2[k]);
    float re[16], im[16];
#pragma unroll
    for (int i = 0; i < 16; ++i) { re[i] = 0.f; im[i] = 0.f; }
    re[0] = 1.f;
    {
      float s0, c0; sincosf(0.5f * red[0], &s0, &c0); APPLY_RY(8, c0, s0);
      float s1, c1; sincosf(0.5f * red[1], &s1, &c1); APPLY_RY(4, c1, s1);
      float s2, c2; sincosf(0.5f * red[2], &s2, &c2); APPLY_RY(2, c2, s2);
      float s3, c3; sincosf(0.5f * red[3], &s3, &c3); APPLY_RY(1, c3, s3);
    }
    for (int lyr = 0; lyr < 3; ++lyr) {
      const float* ql = qw + lyr * 8;
      { float sn, cn; sincosf(0.5f * ql[0], &sn, &cn); APPLY_RY(8, cn, sn); }
      { float sn, cn; sincosf(0.5f * ql[1], &sn, &cn); APPLY_RZ(8, cn, sn); }
      { float sn, cn; sincosf(0.5f * ql[2], &sn, &cn); APPLY_RY(4, cn, sn); }
      { float sn, cn; sincosf(0.5f * ql[3], &sn, &cn); APPLY_RZ(4, cn, sn); }
      { float sn, cn; sincosf(0.5f * ql[4], &sn, &cn); APPLY_RY(2, cn, sn); }
      { float sn, cn; sincosf(0.5f * ql[5], &sn, &cn); APPLY_RZ(2, cn, sn); }
      { float sn, cn; sincosf(0.5f * ql[6], &sn, &cn); APPLY_RY(1, cn, sn); }
      { float sn, cn; sincosf(0.5f * ql[7], &sn, &cn); APPLY_RZ(1, cn, sn); }
      APPLY_CNOT(8, 4);
      APPLY_CNOT(4, 2);
      APPLY_CNOT(2, 1);
      APPLY_CNOT(1, 8);
    }
    float q0 = 0.f, q1 = 0.f, q2 = 0.f, q3 = 0.f;
#pragma unroll
    for (int i = 0; i < 16; ++i) {
      const float pr = fmaf(re[i], re[i], im[i] * im[i]);
      q0 += (i & 8) ? -pr : pr;
      q1 += (i & 4) ? -pr : pr;
      q2 += (i & 2) ? -pr : pr;
      q3 += (i & 1) ? -pr : pr;
    }
    float logit = bc2[0];
#pragma unroll
    for (int j = 0; j < 16; ++j) {
      float a = bc1[j];
      a = fmaf(red[0], Wc1[j],       a);
      a = fmaf(red[1], Wc1[16 + j],  a);
      a = fmaf(red[2], Wc1[32 + j],  a);
      a = fmaf(red[3], Wc1[48 + j],  a);
      a = fmaf(q0,     Wc1[64 + j],  a);
      a = fmaf(q1,     Wc1[80 + j],  a);
      a = fmaf(q2,     Wc1[96 + j],  a);
      a = fmaf(q3,     Wc1[112 + j], a);
      logit = fmaf(fmaxf(a, 0.f), Wc2[j], logit);
    }
    if (cq == 0) out[r0 + s] = logit;
  }
}

// ============ Fallback B: round-1 pure-VALU kernel ============
#define NKT 20
__global__ __launch_bounds__(256) void qfc_fused(
    const float* __restrict__ x, const float* __restrict__ W1,
    const float* __restrict__ b1, const float* __restrict__ W2,
    const float* __restrict__ b2, const float* __restrict__ qw,
    const float* __restrict__ Wc1, const float* __restrict__ bc1,
    const float* __restrict__ Wc2, const float* __restrict__ bc2,
    float* __restrict__ out) {
  __shared__ float lds[16384];
  const int tid = threadIdx.x;
  const int lane = tid & 63;
  const int wv = tid >> 6;
  const int rg = lane >> 3;
  const int cg = lane & 7;
  const int r0 = blockIdx.x * 64;
  float acc[8][8];
#pragma unroll
  for (int i = 0; i < 8; ++i)
#pragma unroll
    for (int j = 0; j < 8; ++j) acc[i][j] = 0.f;
  const float* xrow = x + (size_t)(r0 + lane) * 1280 + wv * 16;
  const int aBase = wv * 1024;
  const int bBase = 8192 + wv * 1024;
  float4 a_st[4], b_st[4];
  auto issue_loads = [&](int kt) {
    const float* ap = xrow + kt * 64;
#pragma unroll
    for (int i = 0; i < 4; ++i) a_st[i] = *(const float4*)(ap + i * 4);
    const float* bp = W1 + kt * 4096 + wv * 1024 + lane * 4;
#pragma unroll
    for (int i = 0; i < 4; ++i) b_st[i] = *(const float4*)(bp + i * 256);
  };
  auto write_stage = [&](int buf) {
    float* A = &lds[buf * 4096 + aBase];
#pragma unroll
    for (int i = 0; i < 4; ++i) {
      float* p = A + i * 256 + lane;
      p[0] = a_st[i].x; p[64] = a_st[i].y; p[128] = a_st[i].z; p[192] = a_st[i].w;
    }
    float* Bp = &lds[buf * 4096 + bBase + lane * 4];
#pragma unroll
    for (int i = 0; i < 4; ++i) *(float4*)(Bp + i * 256) = b_st[i];
  };
  auto compute_tile = [&](int buf) {
#pragma unroll
    for (int m = 0; m < 16; ++m) {
      const float* Ak = &lds[buf * 4096 + aBase + m * 64];
      const float* Bk = &lds[buf * 4096 + bBase + m * 64];
      const float4 a0 = *(const float4*)(Ak + rg * 8);
      const float4 a1 = *(const float4*)(Ak + rg * 8 + 4);
      const float4 c0 = *(const float4*)(Bk + cg * 8);
      const float4 c1 = *(const float4*)(Bk + cg * 8 + 4);
      const float av[8] = {a0.x, a0.y, a0.z, a0.w, a1.x, a1.y, a1.z, a1.w};
      const float bv[8] = {c0.x, c0.y, c0.z, c0.w, c1.x, c1.y, c1.z, c1.w};
#pragma unroll
      for (int i = 0; i < 8; ++i)
#pragma unroll
        for (int j = 0; j < 8; ++j) acc[i][j] = fmaf(av[i], bv[j], acc[i][j]);
    }
  };
  issue_loads(0);
  write_stage(0);
  for (int kt = 0; kt < NKT; ++kt) {
    const int buf = kt & 1;
    if (kt + 1 < NKT) issue_loads(kt + 1);
    compute_tile(buf);
    if (kt + 1 < NKT) write_stage(buf ^ 1);
  }
  __syncthreads();
#pragma unroll
  for (int j = 0; j < 8; ++j) {
    const int c = cg * 8 + j;
    float* p = &lds[wv * 4096 + c * 64 + rg * 8];
    *(float4*)p = make_float4(acc[0][j], acc[1][j], acc[2][j], acc[3][j]);
    *(float4*)(p + 4) = make_float4(acc[4][j], acc[5][j], acc[6][j], acc[7][j]);
  }
  __syncthreads();
  const int s = tid >> 2;
  const int cq = tid & 3;
  float h4[4] = {0.f, 0.f, 0.f, 0.f};
#pragma unroll
  for (int cc = 0; cc < 16; ++cc) {
    const int c = cq * 16 + cc;
    const int o = c * 64 + s;
    float pp = (lds[o] + lds[4096 + o]) + (lds[8192 + o] + lds[12288 + o]);
    float hv = fmaxf(pp + b1[c], 0.f);
    const float4 w2 = *(const float4*)(W2 + c * 4);
    h4[0] = fmaf(hv, w2.x, h4[0]);
    h4[1] = fmaf(hv, w2.y, h4[1]);
    h4[2] = fmaf(hv, w2.z, h4[2]);
    h4[3] = fmaf(hv, w2.w, h4[3]);
  }
#pragma unroll
  for (int k = 0; k < 4; ++k) {
    h4[k] += __shfl_xor(h4[k], 1);
    h4[k] += __shfl_xor(h4[k], 2);
  }
  float red[4];
#pragma unroll
  for (int k = 0; k < 4; ++k) red[k] = tanhf(h4[k] + b2[k]);
  float re[16], im[16];
#pragma unroll
  for (int i = 0; i < 16; ++i) { re[i] = 0.f; im[i] = 0.f; }
  re[0] = 1.f;
  {
    float s0, c0; sincosf(0.5f * red[0], &s0, &c0); APPLY_RY(8, c0, s0);
    float s1, c1; sincosf(0.5f * red[1], &s1, &c1); APPLY_RY(4, c1, s1);
    float s2, c2; sincosf(0.5f * red[2], &s2, &c2); APPLY_RY(2, c2, s2);
    float s3, c3; sincosf(0.5f * red[3], &s3, &c3); APPLY_RY(1, c3, s3);
  }
  for (int lyr = 0; lyr < 3; ++lyr) {
    const float* ql = qw + lyr * 8;
    { float sn, cn; sincosf(0.5f * ql[0], &sn, &cn); APPLY_RY(8, cn, sn); }
    { float sn, cn; sincosf(0.5f * ql[1], &sn, &cn); APPLY_RZ(8, cn, sn); }
    { float sn, cn; sincosf(0.5f * ql[2], &sn, &cn); APPLY_RY(4, cn, sn); }
    { float sn, cn; sincosf(0.5f * ql[3], &sn, &cn); APPLY_RZ(4, cn, sn); }
    { float sn, cn; sincosf(0.5f * ql[4], &sn, &cn); APPLY_RY(2, cn, sn); }
    { float sn, cn; sincosf(0.5f * ql[5], &sn, &cn); APPLY_RZ(2, cn, sn); }
    { float sn, cn; sincosf(0.5f * ql[6], &sn, &cn); APPLY_RY(1, cn, sn); }
    { float sn, cn; sincosf(0.5f * ql[7], &sn, &cn); APPLY_RZ(1, cn, sn); }
    APPLY_CNOT(8, 4);
    APPLY_CNOT(4, 2);
    APPLY_CNOT(2, 1);
    APPLY_CNOT(1, 8);
  }
  float q0 = 0.f, q1 = 0.f, q2 = 0.f, q3 = 0.f;
#pragma unroll
  for (int i = 0; i < 16; ++i) {
    const float pr = fmaf(re[i], re[i], im[i] * im[i]);
    q0 += (i & 8) ? -pr : pr;
    q1 += (i & 4) ? -pr : pr;
    q2 += (i & 2) ? -pr : pr;
    q3 += (i & 1) ? -pr : pr;
  }
  float logit = bc2[0];
#pragma unroll
  for (int j = 0; j < 16; ++j) {
    float a = bc1[j];
    a = fmaf(red[0], Wc1[j],       a);
    a = fmaf(red[1], Wc1[16 + j],  a);
    a = fmaf(red[2], Wc1[32 + j],  a);
    a = fmaf(red[3], Wc1[48 + j],  a);
    a = fmaf(q0,     Wc1[64 + j],  a);
    a = fmaf(q1,     Wc1[80 + j],  a);
    a = fmaf(q2,     Wc1[96 + j],  a);
    a = fmaf(q3,     Wc1[112 + j], a);
    logit = fmaf(fmaxf(a, 0.f), Wc2[j], logit);
  }
  if (cq == 0) out[r0 + s] = logit;
}

extern "C" void kernel_launch(void* const* d_in, const int* in_sizes, int n_in,
                              void* d_out, int out_size, void* d_ws, size_t ws_size,
                              hipStream_t stream) {
  const float* x   = (const float*)d_in[0];
  const float* W1  = (const float*)d_in[1];
  const float* b1  = (const float*)d_in[2];
  const float* W2  = (const float*)d_in[3];
  const float* b2  = (const float*)d_in[4];
  const float* qw  = (const float*)d_in[5];
  const float* Wc1 = (const float*)d_in[6];
  const float* bc1 = (const float*)d_in[7];
  const float* Wc2 = (const float*)d_in[8];
  const float* bc2 = (const float*)d_in[9];

  const size_t WF_BYTES = 327680;                       // W1 frags
  const size_t PW_BYTES = (size_t)1024 * 4096 * 4;      // 16 MB partials
  if (ws_size >= WF_BYTES + PW_BYTES) {
    unsigned short* wf = (unsigned short*)d_ws;
    float* pw = (float*)((char*)d_ws + WF_BYTES);
    prep_w1<<<dim3(40), dim3(256), 0, stream>>>(W1, wf);
    qfc_gemm<<<dim3(1024), dim3(256), 0, stream>>>(x, wf, pw);
    qfc_tail<<<dim3(256), dim3(256), 0, stream>>>(
        pw, b1, W2, b2, qw, Wc1, bc1, Wc2, bc2, (float*)d_out);
  } else if (ws_size >= WF_BYTES) {
    unsigned short* wf = (unsigned short*)d_ws;
    prep_w1<<<dim3(40), dim3(256), 0, stream>>>(W1, wf);
    qfc_mfma4<<<dim3(1024), dim3(256), 0, stream>>>(
        x, wf, b1, W2, b2, qw, Wc1, bc1, Wc2, bc2, (float*)d_out);
  } else {
    qfc_fused<<<dim3(256), dim3(256), 0, stream>>>(
        x, W1, b1, W2, b2, qw, Wc1, bc1, Wc2, bc2, (float*)d_out);
  }
}